// Round 12
// baseline (330.319 us; speedup 1.0000x reference)
//
#include <hip/hip_runtime.h>
#include <hip/hip_bf16.h>
#include <math.h>

#define D_DIM 512
#define TM    128
#define TN    256

typedef int i32x4 __attribute__((ext_vector_type(4)));
typedef unsigned long long u64;

// ---- helpers ---------------------------------------------------------------

__device__ inline void async16(unsigned char* lds, const unsigned char* g) {
    __builtin_amdgcn_global_load_lds(
        (const __attribute__((address_space(1))) void*)g,
        (__attribute__((address_space(3))) void*)lds,
        16, 0, 0);
}

// affinity decode: XCD x = l&7 owns cols {x, 31-x, x+8, 23-x} (132 tiles ea)
__device__ inline bool decode_tile(int l, int& bi, int& bj) {
    const int x    = l & 7;
    const int rank = l >> 3;
    if (rank >= 132) return false;
    const int L0 = 2 * x + 2;
    if (rank < L0)              { bj = x;      bi = rank; }
    else if (rank < 66)         { bj = 31 - x; bi = rank - L0; }
    else if (rank < 2 * x + 84) { bj = x + 8;  bi = rank - 66; }
    else                        { bj = 23 - x; bi = rank - (2 * x + 84); }
    return true;
}

// ---- kernel 1: row L2-normalize -> int8 (x127), init best/acc/cnt ----------

__global__ __launch_bounds__(256) void normalize_rows(
        const float* __restrict__ in, unsigned char* __restrict__ xb,
        float* __restrict__ inv_norm, u64* __restrict__ best,
        float* __restrict__ acc, int* __restrict__ cnt) {
    const int row  = blockIdx.x * 4 + (threadIdx.x >> 6);
    const int lane = threadIdx.x & 63;
    if (blockIdx.x == 0 && threadIdx.x == 0) { acc[0] = 0.f; cnt[0] = 0; }
    const float4* rp = (const float4*)(in + (size_t)row * D_DIM) + lane * 2;
    float4 a = rp[0], b = rp[1];
    float s = a.x*a.x + a.y*a.y + a.z*a.z + a.w*a.w
            + b.x*b.x + b.y*b.y + b.z*b.z + b.w*b.w;
    #pragma unroll
    for (int m = 1; m <= 32; m <<= 1) s += __shfl_xor(s, m, 64);
    float inv = 1.0f / fmaxf(sqrtf(s), 1e-8f);
    if (lane == 0) {
        inv_norm[row] = inv;
        best[row] = 0ull;   // below any real packed key
    }
    float sc = inv * 127.0f;   // int8 symmetric quant; |x_norm|<=1 -> no clamp
    int q0 = __float2int_rn(a.x*sc), q1 = __float2int_rn(a.y*sc);
    int q2 = __float2int_rn(a.z*sc), q3 = __float2int_rn(a.w*sc);
    int q4 = __float2int_rn(b.x*sc), q5 = __float2int_rn(b.y*sc);
    int q6 = __float2int_rn(b.z*sc), q7 = __float2int_rn(b.w*sc);
    int lo = (q0 & 255) | ((q1 & 255) << 8) | ((q2 & 255) << 16) | ((q3 & 255) << 24);
    int hi = (q4 & 255) | ((q5 & 255) << 8) | ((q6 & 255) << 16) | ((q7 & 255) << 24);
    ((int2*)(xb + (size_t)row * D_DIM))[lane] = make_int2(lo, hi);
}

// ---- kernel 2: 128x256-tile int8 GEMM + argmax (R26) -----------------------
// Model fitting ALL of R11-R25: gemm time ~= staged bytes / rate(blocks/CU);
// rate = 2.8 TB/s @1blk (R22), 5.0 @2blk (R17/19/24/25), 6.3 @4blk (R18),
// ~14 @flood. Intra-block schedule (drain/counted/interleave/flags) moved
// results by <= +-3us; block-level concurrency is the knob (per-block
// in-flight caps at ~1 tile for any LDS-feasible pipeline).
// R26: the efficient 128x256 / 203 MB geometry at 4 BLOCKS/CU, 32 waves/CU
// (never reached before): single-buffer BK=64 (24KB tiles + 4KB separate
// merge = 28KB LDS -> 4 blocks; 512thr x 4 = 2048 = max), VGPR 64 (8
// waves/SIMD step), simple drain __syncthreads pairs (R11/R18-proven).
// Swizzle (both sides, rule #21): src slot ((t&3)^((t>>3)&3)), read slot
// quad^((qr>>1)&3) -> 2 lanes/bank, zero conflicts (verified R17-R25).
// u32 tile-local keys (R17). Affinity decode (R20).
// NOTE (R12-R14): do NOT fuse the neighbor gather into this kernel.

__global__ __launch_bounds__(512, 8) void gemm_argmax(
        const unsigned char* __restrict__ X, u64* __restrict__ best) {
    __shared__ unsigned char As[8192];       // 128 rows x 64B
    __shared__ unsigned char Bs[16384];      // 256 rows x 64B
    __shared__ unsigned int rmerge[TM * 4];  // 2 KB (separate, no alias)
    __shared__ unsigned int cmerge[TN * 2];  // 2 KB

    int bi, bj;
    if (!decode_tile(blockIdx.x, bi, bj)) return;
    const int m0 = bi * TM;
    const int n0 = bj * TN;

    const int t    = threadIdx.x;
    const int lane = t & 63;
    const int w    = t >> 6;            // 0..7
    const int wm   = w >> 2;            // row half   (64 rows)
    const int wn   = w & 3;             // col quarter (64 cols)
    const int qr   = lane & 15;
    const int quad = lane >> 4;

    const int srcsl = ((t & 3) ^ ((t >> 3) & 3)) * 16;
    const unsigned char* gA  = X + (size_t)(m0 + (t >> 2)) * D_DIM + srcsl;
    const unsigned char* gB  = X + (size_t)(n0 + (t >> 2)) * D_DIM + srcsl;
    const unsigned char* gB2 = gB + (size_t)128 * D_DIM;

    i32x4 accm[4][4];
    #pragma unroll
    for (int mi = 0; mi < 4; mi++)
        #pragma unroll
        for (int ni = 0; ni < 4; ni++)
            accm[mi][ni] = (i32x4){0, 0, 0, 0};

    const int rdsl = (quad ^ ((qr >> 1) & 3)) * 16;   // read-side swizzle

    #pragma unroll
    for (int kt = 0; kt < 8; kt++) {
        const int k0 = kt * 64;
        async16(As + t * 16,        gA + k0);
        async16(Bs + t * 16,        gB + k0);
        async16(Bs + 8192 + t * 16, gB2 + k0);
        __syncthreads();                 // vmcnt(0)+lgkmcnt(0) drain + barrier

        i32x4 av[4], bv[4];
        const unsigned char* pA = As + (wm * 64 + qr) * 64 + rdsl;
        const unsigned char* pB = Bs + (wn * 64 + qr) * 64 + rdsl;
        #pragma unroll
        for (int mi = 0; mi < 4; mi++)
            av[mi] = *(const i32x4*)(pA + mi * 1024);
        #pragma unroll
        for (int ni = 0; ni < 4; ni++)
            bv[ni] = *(const i32x4*)(pB + ni * 1024);
        #pragma unroll
        for (int mi = 0; mi < 4; mi++)
            #pragma unroll
            for (int ni = 0; ni < 4; ni++)
                accm[mi][ni] = __builtin_amdgcn_mfma_i32_16x16x64_i8(
                    av[mi], bv[ni], accm[mi][ni], 0, 0, 0);

        __syncthreads();                 // reads consumed; safe to overwrite
    }

    // ---- epilogue: u32 tile-local keys (R20 verbatim) ----------------------
    const int colg_base = n0 + wn * 64 + qr;          // + ni*16

    #pragma unroll
    for (int mi = 0; mi < 4; mi++) {
        #pragma unroll
        for (int r = 0; r < 4; r++) {
            const int rowl = wm * 64 + mi * 16 + quad * 4 + r;
            const int rowg = m0 + rowl;
            unsigned key = 0u;
            #pragma unroll
            for (int ni = 0; ni < 4; ni++) {
                const int colg = colg_base + ni * 16;
                const unsigned lcol = (unsigned)(wn * 64 + ni * 16 + qr);
                unsigned k = (((unsigned)accm[mi][ni][r] + 0x800000u) << 8)
                           | (255u - lcol);
                k = (colg == rowg) ? 0u : k;
                key = key > k ? key : k;
            }
            #pragma unroll
            for (int m = 1; m <= 8; m <<= 1) {
                unsigned o = (unsigned)__shfl_xor((int)key, m, 64);
                key = key > o ? key : o;
            }
            if (qr == 0) rmerge[rowl * 4 + wn] = key;
        }
    }

    #pragma unroll
    for (int ni = 0; ni < 4; ni++) {
        const int colg = colg_base + ni * 16;
        unsigned key = 0u;
        #pragma unroll
        for (int mi = 0; mi < 4; mi++) {
            #pragma unroll
            for (int r = 0; r < 4; r++) {
                const unsigned lrow = (unsigned)(wm * 64 + mi * 16 + quad * 4 + r);
                const int rowg = m0 + (int)lrow;
                unsigned k = (((unsigned)accm[mi][ni][r] + 0x800000u) << 8)
                           | (255u - lrow);
                k = (rowg == colg) ? 0u : k;
                key = key > k ? key : k;
            }
        }
        unsigned o = (unsigned)__shfl_xor((int)key, 16, 64);
        key = key > o ? key : o;
        o = (unsigned)__shfl_xor((int)key, 32, 64);
        key = key > o ? key : o;
        if (quad == 0) cmerge[(wn * 64 + ni * 16 + qr) * 2 + wm] = key;
    }
    __syncthreads();

    if (t < TM) {
        unsigned a0 = rmerge[t * 4], a1 = rmerge[t * 4 + 1];
        unsigned a2 = rmerge[t * 4 + 2], a3 = rmerge[t * 4 + 3];
        unsigned k01 = a0 > a1 ? a0 : a1;
        unsigned k23 = a2 > a3 ? a2 : a3;
        unsigned k = k01 > k23 ? k01 : k23;
        // expand to global u64 key: bd32 = dot + 2^31, tie-break smaller col
        unsigned bd32 = (k >> 8) + 0x7F800000u;
        unsigned colg = (unsigned)(n0 + 255) - (k & 255u);
        u64 kk = ((u64)bd32 << 32) | (u64)(0xFFFFFFFFu - colg);
        atomicMax(&best[m0 + t], kk);
    }
    if (t < TN) {
        unsigned c0 = cmerge[t * 2], c1 = cmerge[t * 2 + 1];
        unsigned k = c0 > c1 ? c0 : c1;
        unsigned bd32 = (k >> 8) + 0x7F800000u;
        unsigned rowg = (unsigned)(m0 + 255) - (k & 255u);
        u64 kk = ((u64)bd32 << 32) | (u64)(0xFFFFFFFFu - rowg);
        atomicMax(&best[n0 + t], kk);
    }
}

// ---- kernel 3: exact fp32 distance + fused mean (256-block cheap ticket) ---

__global__ __launch_bounds__(256) void neighbor_reduce(
        const float* __restrict__ in, const float* __restrict__ inv_norm,
        const u64* __restrict__ best, float* __restrict__ acc,
        int* __restrict__ cnt, float* __restrict__ out, int B) {
    const int wave = threadIdx.x >> 6;
    const int lane = threadIdx.x & 63;
    float lsum = 0.f;
    #pragma unroll
    for (int rr = 0; rr < 8; rr++) {
        const int row = blockIdx.x * 32 + wave * 8 + rr;
        u64 k   = best[row];
        int nbr = (int)(0xFFFFFFFFu - (unsigned)(k & 0xFFFFFFFFull));
        float ir  = inv_norm[row];
        float inb = inv_norm[nbr];
        const float4* rp = (const float4*)(in + (size_t)row * D_DIM) + lane * 2;
        const float4* np = (const float4*)(in + (size_t)nbr * D_DIM) + lane * 2;
        float4 r0 = rp[0], r1 = rp[1], q0 = np[0], q1 = np[1];
        float d0 = r0.x*ir - q0.x*inb + 1e-8f, d1 = r0.y*ir - q0.y*inb + 1e-8f;
        float d2 = r0.z*ir - q0.z*inb + 1e-8f, d3 = r0.w*ir - q0.w*inb + 1e-8f;
        float d4 = r1.x*ir - q1.x*inb + 1e-8f, d5 = r1.y*ir - q1.y*inb + 1e-8f;
        float d6 = r1.z*ir - q1.z*inb + 1e-8f, d7 = r1.w*ir - q1.w*inb + 1e-8f;
        float s = d0*d0 + d1*d1 + d2*d2 + d3*d3 + d4*d4 + d5*d5 + d6*d6 + d7*d7;
        #pragma unroll
        for (int m = 1; m <= 32; m <<= 1) s += __shfl_xor(s, m, 64);
        if (lane == 0) lsum += logf(sqrtf(s) + 1e-8f);
    }
    __shared__ float sb[4];
    if (lane == 0) sb[wave] = lsum;
    __syncthreads();
    if (threadIdx.x == 0) {
        float partial = sb[0] + sb[1] + sb[2] + sb[3];
        atomicAdd(acc, partial);
        __threadfence();
        int done = atomicAdd(cnt, 1);
        if (done == gridDim.x - 1) {
            __threadfence();
            float tot = atomicAdd(acc, 0.0f);   // device-scope read of final sum
            out[0] = -tot / (float)B;
        }
    }
}

// ---- launch ----------------------------------------------------------------

extern "C" void kernel_launch(void* const* d_in, const int* in_sizes, int n_in,
                              void* d_out, int out_size, void* d_ws, size_t ws_size,
                              hipStream_t stream) {
    const float* in = (const float*)d_in[0];
    const int B = in_sizes[0] / D_DIM;          // 8192
    const int nblk = 144 * 8;                   // 1152: 144 ranks x 8 XCDs

    char* w = (char*)d_ws;
    unsigned char* xb = (unsigned char*)w;                     // B*D int8
    float* invn = (float*)(w + (size_t)B * D_DIM);
    u64*   best = (u64*)(w + (size_t)B * D_DIM + (size_t)B * 4);
    float* acc  = (float*)(w + (size_t)B * D_DIM + (size_t)B * 4 + (size_t)B * 8);
    int*   cnt  = (int*)(acc + 1);
    float* out  = (float*)d_out;

    normalize_rows<<<B / 4, 256, 0, stream>>>(in, xb, invn, best, acc, cnt);
    gemm_argmax<<<nblk, 512, 0, stream>>>(xb, best);
    neighbor_reduce<<<B / 32, 256, 0, stream>>>(in, invn, best, acc, cnt, out, B);
}

// Round 13
// 106.065 us; speedup vs baseline: 3.1143x; 3.1143x over previous
//
#include <hip/hip_runtime.h>
#include <hip/hip_bf16.h>
#include <math.h>

#define D_DIM 512
#define TM    128
#define TN    256

typedef int i32x4 __attribute__((ext_vector_type(4)));
typedef unsigned long long u64;

// ---- helpers ---------------------------------------------------------------

__device__ inline void async16(unsigned char* lds, const unsigned char* g) {
    __builtin_amdgcn_global_load_lds(
        (const __attribute__((address_space(1))) void*)g,
        (__attribute__((address_space(3))) void*)lds,
        16, 0, 0);
}

// affinity decode: XCD x = l&7 owns cols {x, 31-x, x+8, 23-x} (132 tiles ea)
__device__ inline bool decode_tile(int l, int& bi, int& bj) {
    const int x    = l & 7;
    const int rank = l >> 3;
    if (rank >= 132) return false;
    const int L0 = 2 * x + 2;
    if (rank < L0)              { bj = x;      bi = rank; }
    else if (rank < 66)         { bj = 31 - x; bi = rank - L0; }
    else if (rank < 2 * x + 84) { bj = x + 8;  bi = rank - 66; }
    else                        { bj = 23 - x; bi = rank - (2 * x + 84); }
    return true;
}

// ---- kernel 1: row L2-normalize -> int8 (x127), init best/acc/cnt ----------

__global__ __launch_bounds__(256) void normalize_rows(
        const float* __restrict__ in, unsigned char* __restrict__ xb,
        float* __restrict__ inv_norm, u64* __restrict__ best,
        float* __restrict__ acc, int* __restrict__ cnt) {
    const int row  = blockIdx.x * 4 + (threadIdx.x >> 6);
    const int lane = threadIdx.x & 63;
    if (blockIdx.x == 0 && threadIdx.x == 0) { acc[0] = 0.f; cnt[0] = 0; }
    const float4* rp = (const float4*)(in + (size_t)row * D_DIM) + lane * 2;
    float4 a = rp[0], b = rp[1];
    float s = a.x*a.x + a.y*a.y + a.z*a.z + a.w*a.w
            + b.x*b.x + b.y*b.y + b.z*b.z + b.w*b.w;
    #pragma unroll
    for (int m = 1; m <= 32; m <<= 1) s += __shfl_xor(s, m, 64);
    float inv = 1.0f / fmaxf(sqrtf(s), 1e-8f);
    if (lane == 0) {
        inv_norm[row] = inv;
        best[row] = 0ull;   // below any real packed key
    }
    float sc = inv * 127.0f;   // int8 symmetric quant; |x_norm|<=1 -> no clamp
    int q0 = __float2int_rn(a.x*sc), q1 = __float2int_rn(a.y*sc);
    int q2 = __float2int_rn(a.z*sc), q3 = __float2int_rn(a.w*sc);
    int q4 = __float2int_rn(b.x*sc), q5 = __float2int_rn(b.y*sc);
    int q6 = __float2int_rn(b.z*sc), q7 = __float2int_rn(b.w*sc);
    int lo = (q0 & 255) | ((q1 & 255) << 8) | ((q2 & 255) << 16) | ((q3 & 255) << 24);
    int hi = (q4 & 255) | ((q5 & 255) << 8) | ((q6 & 255) << 16) | ((q7 & 255) << 24);
    ((int2*)(xb + (size_t)row * D_DIM))[lane] = make_int2(lo, hi);
}

// ---- kernel 2: 128x256-tile int8 GEMM + argmax (R27 = R24 restore) ---------
// R26 post-mortem: __launch_bounds__(512,8) forced <=64 combined regs ->
// accumulator spilled to scratch (VGPR_Count 32, ~1GB HBM spill traffic,
// gemm 260us). Register arithmetic: 64-AGPR acc + ~64 VGPR ~= 128/wave vs
// 512/SIMD pool -> 16 waves/CU is the hard ceiling; 4 blocks/CU at 512thr
// is infeasible, and the 4-block 256thr/128^2 config (R18) pays +31% bytes
// for the same net time. Feasible space mapped (R15-R26); R24 is the
// measured optimum. This is R24 verbatim:
//  - TRIPLE-buffered LDS, ONE barrier per K-step
//  - loads span 2 steps: end-of-step vmcnt(3); never drains to 0 in-loop
//  - 2 phases/step: {ds_read A+B01 | stage A,B0(t+2) | MFMA ni01} then
//    {ds_read B23 | stage B1(t+2) | MFMA ni23}, setprio around MFMA
// Swizzle, decode, u32-key epilogue as verified R17-R25.
// NOTE (R12-R14): do NOT fuse the neighbor gather into this kernel.

__global__ __launch_bounds__(512, 4) void gemm_argmax(
        const unsigned char* __restrict__ X, u64* __restrict__ best) {
    __shared__ unsigned char smem[73728];
    unsigned char* As0 = smem;                       // [3][8192]  A: 128x64B
    unsigned char* Bs0 = smem + 24576;               // [3][16384] B: 256x64B
    unsigned int* rmerge = (unsigned int*)smem;          // [128][4] 2KB (alias)
    unsigned int* cmerge = (unsigned int*)(smem + 2048); // [256][2] 2KB (alias)

    int bi, bj;
    if (!decode_tile(blockIdx.x, bi, bj)) return;
    const int m0 = bi * TM;
    const int n0 = bj * TN;

    const int t    = threadIdx.x;
    const int lane = t & 63;
    const int w    = t >> 6;            // 0..7
    const int wm   = w >> 2;            // row half   (64 rows)
    const int wn   = w & 3;             // col quarter (64 cols)
    const int qr   = lane & 15;
    const int quad = lane >> 4;

    const int srcsl = ((t & 3) ^ ((t >> 3) & 3)) * 16;
    const unsigned char* gA  = X + (size_t)(m0 + (t >> 2)) * D_DIM + srcsl;
    const unsigned char* gB  = X + (size_t)(n0 + (t >> 2)) * D_DIM + srcsl;
    const unsigned char* gB2 = gB + (size_t)128 * D_DIM;

    i32x4 accm[4][4];
    #pragma unroll
    for (int mi = 0; mi < 4; mi++)
        #pragma unroll
        for (int ni = 0; ni < 4; ni++)
            accm[mi][ni] = (i32x4){0, 0, 0, 0};

    const int rdsl = (quad ^ ((qr >> 1) & 3)) * 16;   // read-side swizzle

    // prologue: fill buf0, buf1; wait buf0 only (buf1 stays in flight)
    async16(As0 + t * 16,         gA);
    async16(Bs0 + t * 16,         gB);
    async16(Bs0 + 8192 + t * 16,  gB2);
    async16(As0 + 8192 + t * 16,         gA + 64);
    async16(Bs0 + 16384 + t * 16,        gB + 64);
    async16(Bs0 + 16384 + 8192 + t * 16, gB2 + 64);
    asm volatile("s_waitcnt vmcnt(3)" ::: "memory");
    __builtin_amdgcn_s_barrier();

    #pragma unroll
    for (int t8 = 0; t8 < 8; t8++) {
        const int cur = t8 % 3;               // compile-time (unrolled)
        const int nxt = (t8 + 2) % 3;
        const int k2  = (t8 + 2) * 64;
        const unsigned char* pA = As0 + cur * 8192  + (wm * 64 + qr) * 64 + rdsl;
        const unsigned char* pB = Bs0 + cur * 16384 + (wn * 64 + qr) * 64 + rdsl;

        // ---- phase 0: A-frags + B01 | stage A,B0(t+2) | MFMA ni=0,1 -------
        i32x4 av[4], bv[4];
        #pragma unroll
        for (int mi = 0; mi < 4; mi++)
            av[mi] = *(const i32x4*)(pA + mi * 1024);
        bv[0] = *(const i32x4*)(pB);
        bv[1] = *(const i32x4*)(pB + 1024);
        if (t8 < 6) {
            async16(As0 + nxt * 8192 + t * 16,  gA + k2);
            async16(Bs0 + nxt * 16384 + t * 16, gB + k2);
        }
        __builtin_amdgcn_s_setprio(1);
        #pragma unroll
        for (int mi = 0; mi < 4; mi++) {
            accm[mi][0] = __builtin_amdgcn_mfma_i32_16x16x64_i8(
                av[mi], bv[0], accm[mi][0], 0, 0, 0);
            accm[mi][1] = __builtin_amdgcn_mfma_i32_16x16x64_i8(
                av[mi], bv[1], accm[mi][1], 0, 0, 0);
        }
        __builtin_amdgcn_s_setprio(0);

        // ---- phase 1: B23 | stage B1(t+2) | MFMA ni=2,3 -------------------
        bv[2] = *(const i32x4*)(pB + 2048);
        bv[3] = *(const i32x4*)(pB + 3072);
        if (t8 < 6)
            async16(Bs0 + nxt * 16384 + 8192 + t * 16, gB2 + k2);
        __builtin_amdgcn_s_setprio(1);
        #pragma unroll
        for (int mi = 0; mi < 4; mi++) {
            accm[mi][2] = __builtin_amdgcn_mfma_i32_16x16x64_i8(
                av[mi], bv[2], accm[mi][2], 0, 0, 0);
            accm[mi][3] = __builtin_amdgcn_mfma_i32_16x16x64_i8(
                av[mi], bv[3], accm[mi][3], 0, 0, 0);
        }
        __builtin_amdgcn_s_setprio(0);

        // ---- step end: buf[t+1] landed; ONE barrier -----------------------
        asm volatile("" ::: "memory");       // keep this step's LDS reads above
        if (t8 < 6) {
            asm volatile("s_waitcnt vmcnt(3)" ::: "memory");
        } else {
            asm volatile("s_waitcnt vmcnt(0)" ::: "memory");
        }
        __builtin_amdgcn_s_barrier();
    }

    // ---- epilogue: u32 tile-local keys (R20 verbatim) ----------------------
    const int colg_base = n0 + wn * 64 + qr;          // + ni*16

    #pragma unroll
    for (int mi = 0; mi < 4; mi++) {
        #pragma unroll
        for (int r = 0; r < 4; r++) {
            const int rowl = wm * 64 + mi * 16 + quad * 4 + r;
            const int rowg = m0 + rowl;
            unsigned key = 0u;
            #pragma unroll
            for (int ni = 0; ni < 4; ni++) {
                const int colg = colg_base + ni * 16;
                const unsigned lcol = (unsigned)(wn * 64 + ni * 16 + qr);
                unsigned k = (((unsigned)accm[mi][ni][r] + 0x800000u) << 8)
                           | (255u - lcol);
                k = (colg == rowg) ? 0u : k;
                key = key > k ? key : k;
            }
            #pragma unroll
            for (int m = 1; m <= 8; m <<= 1) {
                unsigned o = (unsigned)__shfl_xor((int)key, m, 64);
                key = key > o ? key : o;
            }
            if (qr == 0) rmerge[rowl * 4 + wn] = key;
        }
    }

    #pragma unroll
    for (int ni = 0; ni < 4; ni++) {
        const int colg = colg_base + ni * 16;
        unsigned key = 0u;
        #pragma unroll
        for (int mi = 0; mi < 4; mi++) {
            #pragma unroll
            for (int r = 0; r < 4; r++) {
                const unsigned lrow = (unsigned)(wm * 64 + mi * 16 + quad * 4 + r);
                const int rowg = m0 + (int)lrow;
                unsigned k = (((unsigned)accm[mi][ni][r] + 0x800000u) << 8)
                           | (255u - lrow);
                k = (rowg == colg) ? 0u : k;
                key = key > k ? key : k;
            }
        }
        unsigned o = (unsigned)__shfl_xor((int)key, 16, 64);
        key = key > o ? key : o;
        o = (unsigned)__shfl_xor((int)key, 32, 64);
        key = key > o ? key : o;
        if (quad == 0) cmerge[(wn * 64 + ni * 16 + qr) * 2 + wm] = key;
    }
    __syncthreads();

    if (t < TM) {
        unsigned a0 = rmerge[t * 4], a1 = rmerge[t * 4 + 1];
        unsigned a2 = rmerge[t * 4 + 2], a3 = rmerge[t * 4 + 3];
        unsigned k01 = a0 > a1 ? a0 : a1;
        unsigned k23 = a2 > a3 ? a2 : a3;
        unsigned k = k01 > k23 ? k01 : k23;
        unsigned bd32 = (k >> 8) + 0x7F800000u;
        unsigned colg = (unsigned)(n0 + 255) - (k & 255u);
        u64 kk = ((u64)bd32 << 32) | (u64)(0xFFFFFFFFu - colg);
        atomicMax(&best[m0 + t], kk);
    }
    if (t < TN) {
        unsigned c0 = cmerge[t * 2], c1 = cmerge[t * 2 + 1];
        unsigned k = c0 > c1 ? c0 : c1;
        unsigned bd32 = (k >> 8) + 0x7F800000u;
        unsigned rowg = (unsigned)(m0 + 255) - (k & 255u);
        u64 kk = ((u64)bd32 << 32) | (u64)(0xFFFFFFFFu - rowg);
        atomicMax(&best[n0 + t], kk);
    }
}

// ---- kernel 3: exact fp32 distance + fused mean (256-block cheap ticket) ---

__global__ __launch_bounds__(256) void neighbor_reduce(
        const float* __restrict__ in, const float* __restrict__ inv_norm,
        const u64* __restrict__ best, float* __restrict__ acc,
        int* __restrict__ cnt, float* __restrict__ out, int B) {
    const int wave = threadIdx.x >> 6;
    const int lane = threadIdx.x & 63;
    float lsum = 0.f;
    #pragma unroll
    for (int rr = 0; rr < 8; rr++) {
        const int row = blockIdx.x * 32 + wave * 8 + rr;
        u64 k   = best[row];
        int nbr = (int)(0xFFFFFFFFu - (unsigned)(k & 0xFFFFFFFFull));
        float ir  = inv_norm[row];
        float inb = inv_norm[nbr];
        const float4* rp = (const float4*)(in + (size_t)row * D_DIM) + lane * 2;
        const float4* np = (const float4*)(in + (size_t)nbr * D_DIM) + lane * 2;
        float4 r0 = rp[0], r1 = rp[1], q0 = np[0], q1 = np[1];
        float d0 = r0.x*ir - q0.x*inb + 1e-8f, d1 = r0.y*ir - q0.y*inb + 1e-8f;
        float d2 = r0.z*ir - q0.z*inb + 1e-8f, d3 = r0.w*ir - q0.w*inb + 1e-8f;
        float d4 = r1.x*ir - q1.x*inb + 1e-8f, d5 = r1.y*ir - q1.y*inb + 1e-8f;
        float d6 = r1.z*ir - q1.z*inb + 1e-8f, d7 = r1.w*ir - q1.w*inb + 1e-8f;
        float s = d0*d0 + d1*d1 + d2*d2 + d3*d3 + d4*d4 + d5*d5 + d6*d6 + d7*d7;
        #pragma unroll
        for (int m = 1; m <= 32; m <<= 1) s += __shfl_xor(s, m, 64);
        if (lane == 0) lsum += logf(sqrtf(s) + 1e-8f);
    }
    __shared__ float sb[4];
    if (lane == 0) sb[wave] = lsum;
    __syncthreads();
    if (threadIdx.x == 0) {
        float partial = sb[0] + sb[1] + sb[2] + sb[3];
        atomicAdd(acc, partial);
        __threadfence();
        int done = atomicAdd(cnt, 1);
        if (done == gridDim.x - 1) {
            __threadfence();
            float tot = atomicAdd(acc, 0.0f);   // device-scope read of final sum
            out[0] = -tot / (float)B;
        }
    }
}

// ---- launch ----------------------------------------------------------------

extern "C" void kernel_launch(void* const* d_in, const int* in_sizes, int n_in,
                              void* d_out, int out_size, void* d_ws, size_t ws_size,
                              hipStream_t stream) {
    const float* in = (const float*)d_in[0];
    const int B = in_sizes[0] / D_DIM;          // 8192
    const int nblk = 144 * 8;                   // 1152: 144 ranks x 8 XCDs

    char* w = (char*)d_ws;
    unsigned char* xb = (unsigned char*)w;                     // B*D int8
    float* invn = (float*)(w + (size_t)B * D_DIM);
    u64*   best = (u64*)(w + (size_t)B * D_DIM + (size_t)B * 4);
    float* acc  = (float*)(w + (size_t)B * D_DIM + (size_t)B * 4 + (size_t)B * 8);
    int*   cnt  = (int*)(acc + 1);
    float* out  = (float*)d_out;

    normalize_rows<<<B / 4, 256, 0, stream>>>(in, xb, invn, best, acc, cnt);
    gemm_argmax<<<nblk, 512, 0, stream>>>(xb, best);
    neighbor_reduce<<<B / 32, 256, 0, stream>>>(in, invn, best, acc, cnt, out, B);
}